// Round 6
// baseline (715.128 us; speedup 1.0000x reference)
//
#include <hip/hip_runtime.h>

#define NPTS 8192
#define DIM 128
#define NCLS 128
#define KSEL 17      // k+1 smallest define the threshold
#define RG 64        // rows per block: one 16-row MFMA set per wave
#define CGN 8        // column groups (1024 cols each)
#define NTIL 64      // 16-col tiles per group
#define CAP 64       // per-row LDS candidate capacity
#define SEG 32       // per-(row,cg) scratch segment (raw-copy limit)
#define BIG 3.0e38f

typedef short bf16x8 __attribute__((ext_vector_type(8)));
typedef float f32x4 __attribute__((ext_vector_type(4)));

__device__ __forceinline__ unsigned short f2bf(float f) {
  unsigned int u = __float_as_uint(f);
  u += 0x7fffu + ((u >> 16) & 1u);   // round-to-nearest-even
  return (unsigned short)(u >> 16);
}

// ---- prep: bf16 X + exact fp32 norms + distributed class stats
// packed[c] = (j0<<16)|j1 : two smallest indices of class c (init 0xFFFFFFFF)
__global__ void prep(const float* __restrict__ X, const long long* __restrict__ targets,
                     unsigned short* __restrict__ Xb, float* __restrict__ sqv,
                     int* __restrict__ tgt, int* __restrict__ ccount,
                     unsigned* __restrict__ packed) {
  const int tid = threadIdx.x;
  const int w = tid >> 6, lane = tid & 63;
  const int gw = blockIdx.x * 4 + w;
  const float* xr = X + (size_t)gw * DIM;
  float a = xr[lane], b = xr[lane + 64];
  Xb[(size_t)gw * DIM + lane] = f2bf(a);
  Xb[(size_t)gw * DIM + lane + 64] = f2bf(b);
  float s = a * a + b * b;
#pragma unroll
  for (int off = 32; off; off >>= 1) s += __shfl_xor(s, off);
  if (lane == 0) {
    sqv[gw] = s;
    int c = (int)targets[gw];
    tgt[gw] = c;
    atomicAdd(&ccount[c], 1);
    unsigned old = packed[c];
    for (;;) {
      unsigned j0 = old >> 16, j1 = old & 0xffffu;
      unsigned g = (unsigned)gw;
      if (g >= j1) break;
      unsigned n0 = (g < j0) ? g : j0;
      unsigned n1 = (g < j0) ? j0 : g;
      unsigned nv = (n0 << 16) | n1;
      unsigned prev = atomicCAS(&packed[c], old, nv);
      if (prev == old) break;
      old = prev;
    }
  }
}

// ---- fused kNN: grid 1024 = 128 row-groups(64 rows) x 8 column-groups(1024 cols).
// Wave w owns rows [rbase+16w, +16); all 4 waves scan the SAME columns (L1 reuse).
// Sweep 1: per-lane min2 -> per-quad 17-extract -> U (val-space, >= group t17).
// Sweep 2: append val <= U to wave-private row buffers (d2, flag in sign bit).
// Finalize: raw-copy (tot<=SEG) or exact 17-extract to scratch.
// Last arriving block of the row-group merges all 8 group-lists + loss epilogue.
__global__ __launch_bounds__(256, 3) void knn_main(
    const unsigned short* __restrict__ Xb, const float* __restrict__ sqv,
    const int* __restrict__ tgt, const int* __restrict__ ccount,
    const unsigned* __restrict__ packed, const float* __restrict__ X32,
    float* scr, int* cscr, unsigned* done, float* out) {
  __shared__ float bufD[RG][CAP];
  __shared__ int cnt[RG];
  __shared__ int lastFlag;
  __shared__ float blockAcc[4];

  const int tid = threadIdx.x;
  const int w = tid >> 6, lane = tid & 63, quad = lane >> 4, l16 = lane & 15;
  const int rg = blockIdx.x >> 3, cg = blockIdx.x & 7;
  const int rbase = rg * RG;
  const int wrow = rbase + w * 16;
  const int colbase = cg * 1024;

  // A fragments (16 rows x K=128). 16x16x32 bf16: A[m=lane&15][k=quad*8+j]
  bf16x8 afrag[4];
  {
    const unsigned short* ar = Xb + (size_t)(wrow + l16) * DIM + quad * 8;
#pragma unroll
    for (int kb = 0; kb < 4; kb++) afrag[kb] = *(const bf16x8*)(ar + kb * 32);
  }
  float sqi[4]; int ti[4], growr[4];
#pragma unroll
  for (int r = 0; r < 4; r++) {
    int rr = wrow + quad * 4 + r;
    sqi[r] = sqv[rr]; ti[r] = tgt[rr]; growr[r] = rr;
  }
  // wave-uniform tile containing this wave's diagonal block (or -1)
  const int dtile = (wrow >= colbase && wrow < colbase + 1024) ? ((wrow - colbase) >> 4) : -1;

  const unsigned short* bb = Xb + (size_t)(colbase + l16) * DIM + quad * 8;
  const float* sqp = sqv + colbase + l16;
  const int*   tgp = tgt + colbase + l16;

  if (lane < 16) cnt[w * 16 + lane] = 0;   // wave-private rows, no barrier needed

#define LOADB(bd, sq, tn) { \
    const unsigned short* p_ = bb + (size_t)(tn) * (16 * DIM); \
    bd[0] = *(const bf16x8*)(p_);      bd[1] = *(const bf16x8*)(p_ + 32); \
    bd[2] = *(const bf16x8*)(p_ + 64); bd[3] = *(const bf16x8*)(p_ + 96); \
    sq = sqp[(tn) * 16]; }

#define MFMA4(bc, acc) { \
    acc = __builtin_amdgcn_mfma_f32_16x16x32_bf16(afrag[0], bc[0], acc, 0, 0, 0); \
    acc = __builtin_amdgcn_mfma_f32_16x16x32_bf16(afrag[1], bc[1], acc, 0, 0, 0); \
    acc = __builtin_amdgcn_mfma_f32_16x16x32_bf16(afrag[2], bc[2], acc, 0, 0, 0); \
    acc = __builtin_amdgcn_mfma_f32_16x16x32_bf16(afrag[3], bc[3], acc, 0, 0, 0); }

  // ---- sweep 1: per-lane two smallest vals (val = sqj - 2*G; row-order invariant)
  float m1[4] = {BIG, BIG, BIG, BIG}, m2[4] = {BIG, BIG, BIG, BIG};
  {
    bf16x8 bA[4], bB[4]; float sqA, sqB;
    LOADB(bA, sqA, 0)
    for (int t = 0; t < NTIL; t += 2) {
      LOADB(bB, sqB, t + 1)
      __builtin_amdgcn_sched_barrier(0);
      {
        f32x4 acc = {0.f, 0.f, 0.f, 0.f};
        MFMA4(bA, acc)
#pragma unroll
        for (int r = 0; r < 4; r++) {
          float v = fmaf(-2.0f, acc[r], sqA);
          m2[r] = fminf(m2[r], fmaxf(m1[r], v));
          m1[r] = fminf(m1[r], v);
        }
      }
      { const int tn = (t + 2 < NTIL) ? t + 2 : NTIL - 1; LOADB(bA, sqA, tn) }
      __builtin_amdgcn_sched_barrier(0);
      {
        f32x4 acc = {0.f, 0.f, 0.f, 0.f};
        MFMA4(bB, acc)
#pragma unroll
        for (int r = 0; r < 4; r++) {
          float v = fmaf(-2.0f, acc[r], sqB);
          m2[r] = fminf(m2[r], fmaxf(m1[r], v));
          m1[r] = fminf(m1[r], v);
        }
      }
    }
  }
  // remove diagonal (it is the strict minimum of its lane) from the subset
  if (dtile >= 0) {
#pragma unroll
    for (int r = 0; r < 4; r++)
      if (l16 == quad * 4 + r) { m1[r] = m2[r]; m2[r] = BIG; }
  }

  // U[r] = 17th smallest of the 32-candidate subset, per-quad (16-lane shuffles)
  float Ur[4];
#pragma unroll
  for (int r = 0; r < 4; r++) {
    float a = m1[r], b = m2[r], v17 = BIG;
    for (int round = 0; round < KSEL; round++) {
      float v = a; int idx = lane;
      if (b < v) { v = b; idx = lane | 64; }
#pragma unroll
      for (int off = 1; off < 16; off <<= 1) {
        float ov = __shfl_xor(v, off);
        int   oi = __shfl_xor(idx, off);
        if (ov < v || (ov == v && oi < idx)) { v = ov; idx = oi; }
      }
      if ((idx & 63) == lane) { if (idx & 64) b = BIG; else a = BIG; }
      v17 = v;
    }
    Ur[r] = v17;
  }

  // ---- sweep 2: append val <= U (encode d2 = val + sqi; same-class flag in sign bit)
  {
    bf16x8 bA[4], bB[4]; float sqA, sqB; int tjA, tjB;
    LOADB(bA, sqA, 0) tjA = tgp[0];
    for (int t = 0; t < NTIL; t += 2) {
      LOADB(bB, sqB, t + 1) tjB = tgp[(t + 1) * 16];
      __builtin_amdgcn_sched_barrier(0);
      {
        f32x4 acc = {0.f, 0.f, 0.f, 0.f};
        MFMA4(bA, acc)
#pragma unroll
        for (int r = 0; r < 4; r++) {
          float v = fmaf(-2.0f, acc[r], sqA);
          if (v <= Ur[r]) {
            int col = colbase + t * 16 + l16;
            if (col != growr[r]) {
              int pos = atomicAdd(&cnt[w * 16 + quad * 4 + r], 1);
              if (pos < CAP) {
                unsigned enc = __float_as_uint(fmaxf(v + sqi[r], 0.0f));
                if (tjA == ti[r]) enc |= 0x80000000u;
                bufD[w * 16 + quad * 4 + r][pos] = __uint_as_float(enc);
              }
            }
          }
        }
      }
      { const int tn = (t + 2 < NTIL) ? t + 2 : NTIL - 1; LOADB(bA, sqA, tn) tjA = tgp[tn * 16]; }
      __builtin_amdgcn_sched_barrier(0);
      {
        f32x4 acc = {0.f, 0.f, 0.f, 0.f};
        MFMA4(bB, acc)
#pragma unroll
        for (int r = 0; r < 4; r++) {
          float v = fmaf(-2.0f, acc[r], sqB);
          if (v <= Ur[r]) {
            int col = colbase + (t + 1) * 16 + l16;
            if (col != growr[r]) {
              int pos = atomicAdd(&cnt[w * 16 + quad * 4 + r], 1);
              if (pos < CAP) {
                unsigned enc = __float_as_uint(fmaxf(v + sqi[r], 0.0f));
                if (tjB == ti[r]) enc |= 0x80000000u;
                bufD[w * 16 + quad * 4 + r][pos] = __uint_as_float(enc);
              }
            }
          }
        }
      }
    }
  }

  // ---- finalize (wave-private rows): raw copy, or exact 17-extract on overflow
  for (int rr = 0; rr < 16; rr++) {
    const int row = w * 16 + rr;
    const int grow = rbase + row;
    const int tot = cnt[row];
    float* srow = scr + (size_t)grow * (CGN * SEG) + cg * SEG;
    if (tot <= SEG) {
      if (lane < tot) srow[lane] = bufD[row][lane];
      if (lane == 0) cscr[grow * CGN + cg] = tot;
    } else {
      const int n = min(tot, CAP);
      float e; int m;
      if (lane < n) {
        unsigned u = __float_as_uint(bufD[row][lane]);
        m = (int)(u >> 31); e = __uint_as_float(u & 0x7fffffffu);
      } else { e = BIG; m = 0; }
      for (int round = 0; round < KSEL; round++) {
        float v = e; int idx = lane;
#pragma unroll
        for (int off = 1; off < 64; off <<= 1) {
          float ov = __shfl_xor(v, off);
          int   oi = __shfl_xor(idx, off);
          if (ov < v || (ov == v && oi < idx)) { v = ov; idx = oi; }
        }
        if (idx == lane) {
          unsigned ub = __float_as_uint(e);
          if (m) ub |= 0x80000000u;
          srow[round] = __uint_as_float(ub);
          e = BIG;
        }
      }
      if (lane == 0) cscr[grow * CGN + cg] = KSEL;
    }
  }

  // ---- last block of the row-group merges all 8 group-lists
  __threadfence();
  __syncthreads();
  if (tid == 0) lastFlag = (atomicAdd(&done[rg], 1u) == CGN - 1);
  __syncthreads();
  if (!lastFlag) return;
  if (tid < 4) blockAcc[tid] = 0.0f;
  __syncthreads();
  __threadfence();   // acquire: invalidate stale cached lines before reading peers' scr

  float aloss = 0.f, aacc = 0.f, atp = 0.f, atn = 0.f;
  for (int rr = 0; rr < 16; rr++) {
    const int row = rbase + w * 16 + rr;
    const int cnt8 = (lane < 8) ? cscr[row * CGN + lane] : 0;
    float e[4]; int m[4];
#pragma unroll
    for (int k = 0; k < 4; k++) {
      const int s = lane + 64 * k;
      const int ck = __shfl(cnt8, s >> 5);
      if ((s & 31) < ck) {
        unsigned u = __float_as_uint(scr[(size_t)row * (CGN * SEG) + s]);
        m[k] = (int)(u >> 31); e[k] = __uint_as_float(u & 0x7fffffffu);
      } else { e[k] = BIG; m[k] = 0; }
    }
    float w0 = e[0], w1 = e[1], w2 = e[2], w3 = e[3], t17 = BIG;
    for (int round = 0; round < KSEL; round++) {
      float v = w0; int idx = lane;
      if (w1 < v) { v = w1; idx = lane | (1 << 6); }
      if (w2 < v) { v = w2; idx = lane | (2 << 6); }
      if (w3 < v) { v = w3; idx = lane | (3 << 6); }
#pragma unroll
      for (int off = 1; off < 64; off <<= 1) {
        float ov = __shfl_xor(v, off);
        int   oi = __shfl_xor(idx, off);
        if (ov < v || (ov == v && oi < idx)) { v = ov; idx = oi; }
      }
      if ((idx & 63) == lane) {
        int k = idx >> 6;
        if (k == 0) w0 = BIG; else if (k == 1) w1 = BIG; else if (k == 2) w2 = BIG; else w3 = BIG;
      }
      t17 = v;
    }
    float pls = 0.f, nls = 0.f; int cp = 0, cn = 0;
#pragma unroll
    for (int k = 0; k < 4; k++) {
      if (e[k] < t17) {                       // strict, matches reference
        float ex = expf(-sqrtf(fmaxf(e[k], 1e-12f)));
        if (m[k]) { pls += ex; cp++; } else { nls += ex; cn++; }
      }
    }
#pragma unroll
    for (int off = 32; off; off >>= 1) {
      pls += __shfl_xor(pls, off); nls += __shfl_xor(nls, off);
      cp  += __shfl_xor(cp, off);  cn  += __shfl_xor(cn, off);
    }
    const int c = tgt[row];
    const int ncl = ccount[c];
    if ((ncl > 1) && (ncl < NPTS)) {
      float pos_eff;
      if (cp == 0) {
        const unsigned pk = packed[c];
        const int j0 = (int)(pk >> 16), j1 = (int)(pk & 0xffffu);
        const int jf = (row == j0) ? j1 : j0;
        const float* xi = X32 + (size_t)row * DIM;
        const float* xj = X32 + (size_t)jf * DIM;
        float pp = xi[lane] * xj[lane] + xi[lane + 64] * xj[lane + 64];
#pragma unroll
        for (int off = 32; off; off >>= 1) pp += __shfl_xor(pp, off);
        const float fb2 = sqv[row] + sqv[jf] - 2.0f * pp;
        pos_eff = expf(-sqrtf(fmaxf(fb2, 1e-12f)));
      } else {
        pos_eff = pls;
      }
      aloss += -logf(pos_eff / (pos_eff + nls));
      aacc  += (((cp == 0) ? 1 : cp) > cn) ? 1.0f : 0.0f;
      atp   += (float)cp;
      atn   += (float)cn;
    }
  }
  if (lane == 0) {
    atomicAdd(&blockAcc[0], aloss);
    atomicAdd(&blockAcc[1], aacc);
    atomicAdd(&blockAcc[2], atp);
    atomicAdd(&blockAcc[3], atn);
  }
  __syncthreads();
  if (tid < 4) atomicAdd(&out[tid], blockAcc[tid] * (1.0f / (float)NPTS));
#undef LOADB
#undef MFMA4
}

extern "C" void kernel_launch(void* const* d_in, const int* in_sizes, int n_in,
                              void* d_out, int out_size, void* d_ws, size_t ws_size,
                              hipStream_t stream) {
  const float* X = (const float*)d_in[0];
  const long long* targets = (const long long*)d_in[1];
  float* out = (float*)d_out;

  char* ws = (char*)d_ws;
  unsigned short* Xb = (unsigned short*)ws;                          // 2 MiB
  float* sqv    = (float*)   (ws + (2u << 20));                      // 32 KiB
  int*   tgt    = (int*)     (ws + (2u << 20) + (32u << 10));        // 32 KiB
  int*   ccount = (int*)     (ws + (2u << 20) + (64u << 10));        // 512 B
  unsigned* done = (unsigned*)(ws + (2u << 20) + (64u << 10) + 512); // 512 B
  unsigned* packed = (unsigned*)(ws + (2u << 20) + (65u << 10));     // 512 B
  float* scr = (float*)(ws + (2u << 20) + (128u << 10));             // 8192*8*SEG*4 = 8 MiB
  int* cscr  = (int*)  (ws + (2u << 20) + (128u << 10) + (size_t)NPTS * CGN * SEG * 4); // 256 KiB

  hipMemsetAsync(d_out, 0, 4 * sizeof(float), stream);
  hipMemsetAsync(ccount, 0, 1024, stream);            // ccount + done
  hipMemsetAsync(packed, 0xFF, NCLS * sizeof(unsigned), stream);
  prep<<<2048, 256, 0, stream>>>(X, targets, Xb, sqv, tgt, ccount, packed);
  knn_main<<<1024, 256, 0, stream>>>(Xb, sqv, tgt, ccount, packed, X, scr, cscr, done, out);
}

// Round 7
// 285.445 us; speedup vs baseline: 2.5053x; 2.5053x over previous
//
#include <hip/hip_runtime.h>

#define NPTS 8192
#define DIM 128
#define NCLS 128
#define KSEL 17      // k+1 smallest define the threshold
#define ROWS 32      // rows per block (two 16-row MFMA sets)
#define CAPW 40      // per-(wave,row) LDS candidate capacity
#define SEG  32      // per-(row,quarter) scratch segment
#define NT   32      // tiles per wave (512 cols / 16)
#define BIG 3.0e38f

typedef short bf16x8 __attribute__((ext_vector_type(8)));
typedef float f32x4 __attribute__((ext_vector_type(4)));

__device__ __forceinline__ unsigned short f2bf(float f) {
  unsigned int u = __float_as_uint(f);
  u += 0x7fffu + ((u >> 16) & 1u);   // round-to-nearest-even
  return (unsigned short)(u >> 16);
}

// order-preserving float <-> uint map (total order, exact inverse)
__device__ __forceinline__ unsigned flipF(float f) {
  unsigned u = __float_as_uint(f);
  return (u & 0x80000000u) ? ~u : (u | 0x80000000u);
}
__device__ __forceinline__ float unflipF(unsigned k) {
  unsigned u = (k & 0x80000000u) ? (k & 0x7fffffffu) : ~k;
  return __uint_as_float(u);
}

// exact KSEL-th smallest of the 128 values {a,b} x 64 lanes, via ballot radix descent.
// ~32 x (2 v_cmp + 2 s_bcnt1) - no LDS latency, no serial swizzle chains.
__device__ __forceinline__ float kth17_2(float a, float b) {
  const unsigned ka = flipF(a), kb = flipF(b);
  unsigned ans = 0;
  for (int bit = 31; bit >= 0; --bit) {
    unsigned mid = ans | (1u << bit);
    int c = __popcll(__ballot(ka < mid)) + __popcll(__ballot(kb < mid));
    if (c < KSEL) ans = mid;
  }
  return unflipF(ans);   // largest v with count(<v) < KSEL == KSEL-th smallest
}
// same over 256 values (4 per lane)
__device__ __forceinline__ float kth17_4(float a, float b, float c_, float d) {
  const unsigned ka = flipF(a), kb = flipF(b), kc = flipF(c_), kd = flipF(d);
  unsigned ans = 0;
  for (int bit = 31; bit >= 0; --bit) {
    unsigned mid = ans | (1u << bit);
    int c = __popcll(__ballot(ka < mid)) + __popcll(__ballot(kb < mid)) +
            __popcll(__ballot(kc < mid)) + __popcll(__ballot(kd < mid));
    if (c < KSEL) ans = mid;
  }
  return unflipF(ans);
}

// ---- prep: bf16 X + exact fp32 norms + distributed class stats
// packed[c]: (j0<<16)|j1 = two smallest indices of class c (init 0xFFFFFFFF)
__global__ void prep(const float* __restrict__ X, const long long* __restrict__ targets,
                     unsigned short* __restrict__ Xb, float* __restrict__ sqv,
                     int* __restrict__ tgt, int* __restrict__ ccount,
                     unsigned* __restrict__ packed) {
  const int tid = threadIdx.x;
  const int w = tid >> 6, lane = tid & 63;
  const int gw = blockIdx.x * 4 + w;
  const float* xr = X + (size_t)gw * DIM;
  float a = xr[lane], b = xr[lane + 64];
  Xb[(size_t)gw * DIM + lane] = f2bf(a);
  Xb[(size_t)gw * DIM + lane + 64] = f2bf(b);
  float s = a * a + b * b;
#pragma unroll
  for (int off = 32; off; off >>= 1) s += __shfl_xor(s, off);
  if (lane == 0) {
    sqv[gw] = s;
    int c = (int)targets[gw];
    tgt[gw] = c;
    atomicAdd(&ccount[c], 1);
    unsigned old = packed[c];
    for (;;) {                       // CAS-insert gw into the class's 2-smallest set
      unsigned j0 = old >> 16, j1 = old & 0xffffu;
      unsigned g = (unsigned)gw;
      if (g >= j1) break;
      unsigned n0 = (g < j0) ? g : j0;
      unsigned n1 = (g < j0) ? j0 : g;
      unsigned nv = (n0 << 16) | n1;
      unsigned prev = atomicCAS(&packed[c], old, nv);
      if (prev == old) break;
      old = prev;
    }
  }
}

// ---- two-sweep kNN: grid 1024 = 256 row-groups(32 rows) x 4 column-quarters.
// Wave w scans cols [quarter*2048 + w*512, +512), two MFMA accumulator chains.
// val = sqj - 2*G tracked (sqi-invariant ordering within a row).
__global__ __launch_bounds__(256, 4) void knn_main(
    const unsigned short* __restrict__ Xb, const float* __restrict__ sqv,
    const int* __restrict__ tgt, float* __restrict__ scr, int* __restrict__ cscr) {
  __shared__ float sh[5120];   // union: cand[32][128] (16KB) / bufD[4][32][CAPW] (20KB)
  __shared__ int   cnt[4][ROWS];
  __shared__ float Uv[ROWS];

  const int tid = threadIdx.x;
  const int w = tid >> 6;
  const int lane = tid & 63;
  const int quad = lane >> 4;
  const int l16 = lane & 15;
  const int rg = blockIdx.x >> 2;
  const int quarter = blockIdx.x & 3;
  const int rbase = rg * ROWS;
  const int colbase = quarter * 2048 + w * 512;

  // A fragments: 2 sets x K=128. 16x16x32 bf16: A[m=lane&15][k=quad*8+j]
  bf16x8 afrag[2][4];
#pragma unroll
  for (int s = 0; s < 2; s++) {
    const unsigned short* arow = Xb + (size_t)(rbase + s * 16 + l16) * DIM + quad * 8;
#pragma unroll
    for (int kb = 0; kb < 4; kb++) afrag[s][kb] = *(const bf16x8*)(arow + kb * 32);
  }
  float sqi[2][4]; int ti[2][4];
#pragma unroll
  for (int s = 0; s < 2; s++)
#pragma unroll
    for (int r = 0; r < 4; r++) {
      int rr = rbase + s * 16 + quad * 4 + r;
      sqi[s][r] = sqv[rr]; ti[s][r] = tgt[rr];
    }

  // wave-uniform diagonal tile per set (or -1)
  int tdiag[2];
#pragma unroll
  for (int s = 0; s < 2; s++) {
    int d = rbase + s * 16 - colbase;
    tdiag[s] = (d >= 0 && d < 512) ? (d >> 4) : -1;
  }

  const unsigned short* bbase = Xb + (size_t)(colbase + l16) * DIM + quad * 8;
  const float* sqp = sqv + colbase + l16;
  const int*   tgp = tgt + colbase + l16;

  // ---- sweep 1: per-lane two smallest vals per row; register double-buffered
  float m1[2][4], m2[2][4];
#pragma unroll
  for (int s = 0; s < 2; s++)
#pragma unroll
    for (int r = 0; r < 4; r++) { m1[s][r] = BIG; m2[s][r] = BIG; }
  {
    bf16x8 bA[4], bB[4]; float sqA, sqB;
#pragma unroll
    for (int kb = 0; kb < 4; kb++) bA[kb] = *(const bf16x8*)(bbase + kb * 32);
    sqA = sqp[0];
    for (int t = 0; t < NT; t += 2) {
      {
        const unsigned short* p = bbase + (size_t)(t + 1) * (16 * DIM);
#pragma unroll
        for (int kb = 0; kb < 4; kb++) bB[kb] = *(const bf16x8*)(p + kb * 32);
        sqB = sqp[(t + 1) * 16];
      }
      {
        f32x4 a0 = {0.f,0.f,0.f,0.f}, a1 = {0.f,0.f,0.f,0.f};
#pragma unroll
        for (int kb = 0; kb < 4; kb++) {
          a0 = __builtin_amdgcn_mfma_f32_16x16x32_bf16(afrag[0][kb], bA[kb], a0, 0, 0, 0);
          a1 = __builtin_amdgcn_mfma_f32_16x16x32_bf16(afrag[1][kb], bA[kb], a1, 0, 0, 0);
        }
#pragma unroll
        for (int s = 0; s < 2; s++) {
#pragma unroll
          for (int r = 0; r < 4; r++) {
            float v = fmaf(-2.0f, (s ? a1[r] : a0[r]), sqA);
            if (t == tdiag[s] && l16 == quad * 4 + r) v = BIG;
            m2[s][r] = fminf(m2[s][r], fmaxf(m1[s][r], v));
            m1[s][r] = fminf(m1[s][r], v);
          }
        }
      }
      {
        const int tn = (t + 2 < NT) ? t + 2 : NT - 1;
        const unsigned short* p = bbase + (size_t)tn * (16 * DIM);
#pragma unroll
        for (int kb = 0; kb < 4; kb++) bA[kb] = *(const bf16x8*)(p + kb * 32);
        sqA = sqp[tn * 16];
      }
      {
        f32x4 a0 = {0.f,0.f,0.f,0.f}, a1 = {0.f,0.f,0.f,0.f};
#pragma unroll
        for (int kb = 0; kb < 4; kb++) {
          a0 = __builtin_amdgcn_mfma_f32_16x16x32_bf16(afrag[0][kb], bB[kb], a0, 0, 0, 0);
          a1 = __builtin_amdgcn_mfma_f32_16x16x32_bf16(afrag[1][kb], bB[kb], a1, 0, 0, 0);
        }
#pragma unroll
        for (int s = 0; s < 2; s++) {
#pragma unroll
          for (int r = 0; r < 4; r++) {
            float v = fmaf(-2.0f, (s ? a1[r] : a0[r]), sqB);
            if (t + 1 == tdiag[s] && l16 == quad * 4 + r) v = BIG;
            m2[s][r] = fminf(m2[s][r], fmaxf(m1[s][r], v));
            m1[s][r] = fminf(m1[s][r], v);
          }
        }
      }
    }
  }
  // publish min2: per row 4 waves x 16 lanes x 2 = 128 candidates (val-space)
#pragma unroll
  for (int s = 0; s < 2; s++)
#pragma unroll
    for (int r = 0; r < 4; r++) {
      int row = s * 16 + quad * 4 + r;
      sh[row * 128 + w * 32 + l16 * 2] = m1[s][r];
      sh[row * 128 + w * 32 + l16 * 2 + 1] = m2[s][r];
    }
  __syncthreads();

  // U[row] = 17th smallest of the 128-candidate subset (radix-select, no swizzle chains)
  for (int ri = 0; ri < 8; ri++) {
    int row = w * 8 + ri;
    float v17 = kth17_2(sh[row * 128 + lane], sh[row * 128 + 64 + lane]);
    if (lane == 0) Uv[row] = v17;
  }
  __syncthreads();
  float Ur[2][4];
#pragma unroll
  for (int s = 0; s < 2; s++)
#pragma unroll
    for (int r = 0; r < 4; r++) Ur[s][r] = Uv[s * 16 + quad * 4 + r];
  if (lane < ROWS) cnt[w][lane] = 0;   // wave-local; ordered before this wave's appends

  // ---- sweep 2: append val <= U (encode d2 = val + sqi, flag in sign bit)
  {
    bf16x8 bA[4], bB[4]; float sqA, sqB; int tjA, tjB;
#pragma unroll
    for (int kb = 0; kb < 4; kb++) bA[kb] = *(const bf16x8*)(bbase + kb * 32);
    sqA = sqp[0]; tjA = tgp[0];
    for (int t = 0; t < NT; t += 2) {
      {
        const unsigned short* p = bbase + (size_t)(t + 1) * (16 * DIM);
#pragma unroll
        for (int kb = 0; kb < 4; kb++) bB[kb] = *(const bf16x8*)(p + kb * 32);
        sqB = sqp[(t + 1) * 16]; tjB = tgp[(t + 1) * 16];
      }
      {
        f32x4 a0 = {0.f,0.f,0.f,0.f}, a1 = {0.f,0.f,0.f,0.f};
#pragma unroll
        for (int kb = 0; kb < 4; kb++) {
          a0 = __builtin_amdgcn_mfma_f32_16x16x32_bf16(afrag[0][kb], bA[kb], a0, 0, 0, 0);
          a1 = __builtin_amdgcn_mfma_f32_16x16x32_bf16(afrag[1][kb], bA[kb], a1, 0, 0, 0);
        }
        float vv[2][4]; bool any = false;
#pragma unroll
        for (int s = 0; s < 2; s++)
#pragma unroll
          for (int r = 0; r < 4; r++) {
            float v = fmaf(-2.0f, (s ? a1[r] : a0[r]), sqA);
            if (t == tdiag[s] && l16 == quad * 4 + r) v = BIG;
            vv[s][r] = v; any |= (v <= Ur[s][r]);
          }
        if (__any(any)) {
#pragma unroll
          for (int s = 0; s < 2; s++)
#pragma unroll
            for (int r = 0; r < 4; r++) {
              if (vv[s][r] <= Ur[s][r]) {
                int rl = s * 16 + quad * 4 + r;
                int pos = atomicAdd(&cnt[w][rl], 1);
                if (pos < CAPW) {
                  unsigned enc = __float_as_uint(fmaxf(vv[s][r] + sqi[s][r], 0.0f));
                  if (tjA == ti[s][r]) enc |= 0x80000000u;
                  sh[(w * ROWS + rl) * CAPW + pos] = __uint_as_float(enc);
                }
              }
            }
        }
      }
      {
        const int tn = (t + 2 < NT) ? t + 2 : NT - 1;
        const unsigned short* p = bbase + (size_t)tn * (16 * DIM);
#pragma unroll
        for (int kb = 0; kb < 4; kb++) bA[kb] = *(const bf16x8*)(p + kb * 32);
        sqA = sqp[tn * 16]; tjA = tgp[tn * 16];
      }
      {
        f32x4 a0 = {0.f,0.f,0.f,0.f}, a1 = {0.f,0.f,0.f,0.f};
#pragma unroll
        for (int kb = 0; kb < 4; kb++) {
          a0 = __builtin_amdgcn_mfma_f32_16x16x32_bf16(afrag[0][kb], bB[kb], a0, 0, 0, 0);
          a1 = __builtin_amdgcn_mfma_f32_16x16x32_bf16(afrag[1][kb], bB[kb], a1, 0, 0, 0);
        }
        float vv[2][4]; bool any = false;
#pragma unroll
        for (int s = 0; s < 2; s++)
#pragma unroll
          for (int r = 0; r < 4; r++) {
            float v = fmaf(-2.0f, (s ? a1[r] : a0[r]), sqB);
            if (t + 1 == tdiag[s] && l16 == quad * 4 + r) v = BIG;
            vv[s][r] = v; any |= (v <= Ur[s][r]);
          }
        if (__any(any)) {
#pragma unroll
          for (int s = 0; s < 2; s++)
#pragma unroll
            for (int r = 0; r < 4; r++) {
              if (vv[s][r] <= Ur[s][r]) {
                int rl = s * 16 + quad * 4 + r;
                int pos = atomicAdd(&cnt[w][rl], 1);
                if (pos < CAPW) {
                  unsigned enc = __float_as_uint(fmaxf(vv[s][r] + sqi[s][r], 0.0f));
                  if (tjB == ti[s][r]) enc |= 0x80000000u;
                  sh[(w * ROWS + rl) * CAPW + pos] = __uint_as_float(enc);
                }
              }
            }
        }
      }
    }
  }
  __syncthreads();

  // ---- finalize: raw-copy candidate lists (common) or 17-extract (overflow, rare)
  for (int rl = 0; rl < ROWS; rl++) {
    const int c0 = min(cnt[0][rl], CAPW), c1 = min(cnt[1][rl], CAPW),
              c2 = min(cnt[2][rl], CAPW), c3 = min(cnt[3][rl], CAPW);
    const int tot = c0 + c1 + c2 + c3;
    const int grow = rbase + rl;
    float* srow = scr + (size_t)grow * (4 * SEG) + quarter * SEG;
    if (tot <= SEG) {
      const int pre = (w > 0 ? c0 : 0) + (w > 1 ? c1 : 0) + (w > 2 ? c2 : 0);
      const int myc = (w == 0) ? c0 : ((w == 1) ? c1 : ((w == 2) ? c2 : c3));
      if (lane < myc) srow[pre + lane] = sh[(w * ROWS + rl) * CAPW + lane];
      if (tid == 0) cscr[grow * 4 + quarter] = tot;
    } else if (w == (rl & 3)) {
      float e[4]; int m[4];
#pragma unroll
      for (int ww = 0; ww < 4; ww++) {
        int n = min(cnt[ww][rl], CAPW);
        if (lane < n) {
          unsigned u = __float_as_uint(sh[(ww * ROWS + rl) * CAPW + lane]);
          m[ww] = (int)(u >> 31); e[ww] = __uint_as_float(u & 0x7fffffffu);
        } else { e[ww] = BIG; m[ww] = 0; }
      }
      for (int round = 0; round < KSEL; round++) {
        float v = e[0]; int idx = lane;
        if (e[1] < v) { v = e[1]; idx = lane | (1 << 6); }
        if (e[2] < v) { v = e[2]; idx = lane | (2 << 6); }
        if (e[3] < v) { v = e[3]; idx = lane | (3 << 6); }
#pragma unroll
        for (int off = 32; off; off >>= 1) {
          float ov = __shfl_xor(v, off);
          int   oi = __shfl_xor(idx, off);
          if (ov < v || (ov == v && oi < idx)) { v = ov; idx = oi; }
        }
        if ((idx & 63) == lane) {
          int s = idx >> 6;
          unsigned ub = __float_as_uint(e[s]);
          if (m[s]) ub |= 0x80000000u;
          srow[round] = __uint_as_float(ub);
          e[s] = BIG;
        }
      }
      if (lane == 0) cscr[grow * 4 + quarter] = KSEL;
    }
  }
}

// ---- per-row merge of 4 quarter-lists (<=128 candidates) + loss epilogue
__global__ __launch_bounds__(256) void knn_merge(
    const float* __restrict__ scr, const int* __restrict__ cscr,
    const float* __restrict__ sqv, const int* __restrict__ tgt,
    const int* __restrict__ ccount, const unsigned* __restrict__ packed,
    const float* __restrict__ X32, float* __restrict__ out) {
  __shared__ float blockAcc[4];
  const int tid = threadIdx.x;
  const int w = tid >> 6;
  const int lane = tid & 63;
  if (tid < 4) blockAcc[tid] = 0.0f;
  __syncthreads();
  for (int ri = 0; ri < 4; ri++) {
    const int grow = blockIdx.x * 16 + w * 4 + ri;
    const float* srow = scr + (size_t)grow * (4 * SEG);
    const int ca = cscr[grow * 4 + (lane >> 5)];
    const int cb = cscr[grow * 4 + 2 + (lane >> 5)];
    const int li = lane & 31;
    float e0 = BIG, e1 = BIG; int mm0 = 0, mm1 = 0;
    if (li < ca) {
      unsigned u = __float_as_uint(srow[(lane >> 5) * SEG + li]);
      mm0 = (int)(u >> 31); e0 = __uint_as_float(u & 0x7fffffffu);
    }
    if (li < cb) {
      unsigned u = __float_as_uint(srow[(2 + (lane >> 5)) * SEG + li]);
      mm1 = (int)(u >> 31); e1 = __uint_as_float(u & 0x7fffffffu);
    }
    // exact 17th smallest of the union (radix-select)
    const float t17 = kth17_2(e0, e1);
    bool s0 = (e0 < t17), s1 = (e1 < t17);                // strict, matches reference
    float x0 = s0 ? expf(-sqrtf(fmaxf(e0, 1e-12f))) : 0.0f;
    float x1 = s1 ? expf(-sqrtf(fmaxf(e1, 1e-12f))) : 0.0f;
    float pls = (s0 && mm0 ? x0 : 0.0f) + (s1 && mm1 ? x1 : 0.0f);
    float nls = (s0 && !mm0 ? x0 : 0.0f) + (s1 && !mm1 ? x1 : 0.0f);
    int cpn = ((int)(s0 && mm0) + (int)(s1 && mm1)) * 65536 +
              ((int)(s0 && !mm0) + (int)(s1 && !mm1));
#pragma unroll
    for (int off = 32; off; off >>= 1) {
      pls += __shfl_xor(pls, off); nls += __shfl_xor(nls, off);
      cpn += __shfl_xor(cpn, off);
    }
    const int cp = cpn >> 16, cn = cpn & 0xffff;
    const int c = tgt[grow];
    const int ncl = ccount[c];
    const bool valid = (ncl > 1) && (ncl < NPTS);
    if (valid) {
      float pos_eff;
      if (cp == 0) {
        const unsigned pk = packed[c];
        const int j0 = (int)(pk >> 16), j1 = (int)(pk & 0xffffu);
        const int jf = (grow == j0) ? j1 : j0;
        const float* xi = X32 + (size_t)grow * DIM;
        const float* xj = X32 + (size_t)jf * DIM;
        float pp = xi[lane] * xj[lane] + xi[lane + 64] * xj[lane + 64];
#pragma unroll
        for (int off = 32; off; off >>= 1) pp += __shfl_xor(pp, off);
        const float fb2 = sqv[grow] + sqv[jf] - 2.0f * pp;
        pos_eff = expf(-sqrtf(fmaxf(fb2, 1e-12f)));
      } else {
        pos_eff = pls;
      }
      if (lane == 0) {
        const float loss_i = -logf(pos_eff / (pos_eff + nls));
        const int cpa = (cp == 0) ? 1 : cp;
        atomicAdd(&blockAcc[0], loss_i);
        atomicAdd(&blockAcc[1], (cpa > cn) ? 1.0f : 0.0f);
        atomicAdd(&blockAcc[2], (float)cp);
        atomicAdd(&blockAcc[3], (float)cn);
      }
    }
  }
  __syncthreads();
  if (tid < 4) atomicAdd(&out[tid], blockAcc[tid] * (1.0f / (float)NPTS));
}

extern "C" void kernel_launch(void* const* d_in, const int* in_sizes, int n_in,
                              void* d_out, int out_size, void* d_ws, size_t ws_size,
                              hipStream_t stream) {
  const float* X = (const float*)d_in[0];
  const long long* targets = (const long long*)d_in[1];
  float* out = (float*)d_out;

  char* ws = (char*)d_ws;
  unsigned short* Xb = (unsigned short*)ws;                        // 2 MiB
  float* sqv    = (float*)   (ws + (2u << 20));                    // 32 KiB
  int*   tgt    = (int*)     (ws + (2u << 20) + (32u << 10));      // 32 KiB
  int*   ccount = (int*)     (ws + (2u << 20) + (64u << 10));      // 512 B
  unsigned* packed = (unsigned*)(ws + (2u << 20) + (65u << 10));   // 512 B
  float* scr = (float*)(ws + (2u << 20) + (128u << 10));           // 8192*4*SEG*4 = 4 MiB
  int* cscr  = (int*)  (ws + (2u << 20) + (128u << 10) + (size_t)NPTS * 4 * SEG * 4); // 128 KiB

  hipMemsetAsync(d_out, 0, 4 * sizeof(float), stream);
  hipMemsetAsync(ccount, 0, NCLS * sizeof(int), stream);
  hipMemsetAsync(packed, 0xFF, NCLS * sizeof(unsigned), stream);
  prep<<<2048, 256, 0, stream>>>(X, targets, Xb, sqv, tgt, ccount, packed);
  knn_main<<<1024, 256, 0, stream>>>(Xb, sqv, tgt, scr, cscr);
  knn_merge<<<512, 256, 0, stream>>>(scr, cscr, sqv, tgt, ccount, packed, X, out);
}

// Round 8
// 285.116 us; speedup vs baseline: 2.5082x; 1.0012x over previous
//
#include <hip/hip_runtime.h>

#define NPTS 8192
#define DIM 128
#define NCLS 128
#define KSEL 17      // k+1 smallest define the threshold
#define ROWS 32      // rows per block (two 16-row MFMA sets)
#define CAPW 40      // per-(wave,row) LDS candidate capacity
#define SEG  32      // per-(row,quarter) scratch segment
#define NT   32      // tiles per wave (512 cols / 16)
#define BIG 3.0e38f

typedef short bf16x8 __attribute__((ext_vector_type(8)));
typedef float f32x4 __attribute__((ext_vector_type(4)));

__device__ __forceinline__ unsigned short f2bf(float f) {
  unsigned int u = __float_as_uint(f);
  u += 0x7fffu + ((u >> 16) & 1u);   // round-to-nearest-even
  return (unsigned short)(u >> 16);
}

// order-preserving float <-> uint map (total order, exact inverse)
__device__ __forceinline__ unsigned flipF(float f) {
  unsigned u = __float_as_uint(f);
  return (u & 0x80000000u) ? ~u : (u | 0x80000000u);
}
__device__ __forceinline__ float unflipF(unsigned k) {
  unsigned u = (k & 0x80000000u) ? (k & 0x7fffffffu) : ~k;
  return __uint_as_float(u);
}

// exact KSEL-th smallest of the 128 values {a,b} x 64 lanes, via ballot radix descent
__device__ __forceinline__ float kth17_2(float a, float b) {
  const unsigned ka = flipF(a), kb = flipF(b);
  unsigned ans = 0;
  for (int bit = 31; bit >= 0; --bit) {
    unsigned mid = ans | (1u << bit);
    int c = __popcll(__ballot(ka < mid)) + __popcll(__ballot(kb < mid));
    if (c < KSEL) ans = mid;
  }
  return unflipF(ans);   // largest v with count(<v) < KSEL == KSEL-th smallest
}

// ---- prep: blocks 0..2047 build bf16 X + exact norms; block 2048: class stats (LDS)
// + zero-init of done counter and output accumulator (no memsets needed).
__global__ void prep(const float* __restrict__ X, const long long* __restrict__ targets,
                     unsigned short* __restrict__ Xb, float* __restrict__ sqv,
                     int* __restrict__ tgt, int* __restrict__ ccount,
                     int* __restrict__ j0a, int* __restrict__ j1a,
                     unsigned* __restrict__ done, float* __restrict__ acc) {
  const int tid = threadIdx.x;
  if (blockIdx.x == 2048) {
    __shared__ int cc[NCLS], c0[NCLS], c1[NCLS];
    if (tid < NCLS) { cc[tid] = 0; c0[tid] = 0x7fffffff; c1[tid] = 0x7fffffff; }
    __syncthreads();
    for (int j = tid; j < NPTS; j += 256) {
      int c = (int)targets[j];
      tgt[j] = c;
      atomicAdd(&cc[c], 1);
      atomicMin(&c0[c], j);
    }
    __syncthreads();
    for (int j = tid; j < NPTS; j += 256) {
      int c = (int)targets[j];
      if (j != c0[c]) atomicMin(&c1[c], j);
    }
    __syncthreads();
    if (tid < NCLS) { ccount[tid] = cc[tid]; j0a[tid] = c0[tid]; j1a[tid] = c1[tid]; }
    if (tid == 0) *done = 0u;
    if (tid < 4) acc[tid] = 0.0f;
    return;
  }
  const int w = tid >> 6, lane = tid & 63;
  const int gw = blockIdx.x * 4 + w;
  const float* xr = X + (size_t)gw * DIM;
  float a = xr[lane], b = xr[lane + 64];
  Xb[(size_t)gw * DIM + lane] = f2bf(a);
  Xb[(size_t)gw * DIM + lane + 64] = f2bf(b);
  float s = a * a + b * b;
#pragma unroll
  for (int off = 32; off; off >>= 1) s += __shfl_xor(s, off);
  if (lane == 0) sqv[gw] = s;
}

// ---- two-sweep kNN: grid 1024 = 256 row-groups(32 rows) x 4 column-quarters.
// Wave w scans cols [quarter*2048 + w*512, +512), two MFMA accumulator chains,
// depth-2 software pipeline (3 register buffer sets, unroll-by-3).
// val = sqj - 2*G tracked (sqi-invariant ordering within a row).
__global__ __launch_bounds__(256, 4) void knn_main(
    const unsigned short* __restrict__ Xb, const float* __restrict__ sqv,
    const int* __restrict__ tgt, float* __restrict__ scr, int* __restrict__ cscr) {
  __shared__ float sh[5120];   // union: cand[32][128] (16KB) / bufD[4][32][CAPW] (20KB)
  __shared__ int   cnt[4][ROWS];
  __shared__ float Uv[ROWS];

  const int tid = threadIdx.x;
  const int w = tid >> 6;
  const int lane = tid & 63;
  const int quad = lane >> 4;
  const int l16 = lane & 15;
  const int rg = blockIdx.x >> 2;
  const int quarter = blockIdx.x & 3;
  const int rbase = rg * ROWS;
  const int colbase = quarter * 2048 + w * 512;

  // A fragments: 2 sets x K=128. 16x16x32 bf16: A[m=lane&15][k=quad*8+j]
  bf16x8 afrag[2][4];
#pragma unroll
  for (int s = 0; s < 2; s++) {
    const unsigned short* arow = Xb + (size_t)(rbase + s * 16 + l16) * DIM + quad * 8;
#pragma unroll
    for (int kb = 0; kb < 4; kb++) afrag[s][kb] = *(const bf16x8*)(arow + kb * 32);
  }
  float sqi[2][4]; int ti[2][4];
#pragma unroll
  for (int s = 0; s < 2; s++)
#pragma unroll
    for (int r = 0; r < 4; r++) {
      int rr = rbase + s * 16 + quad * 4 + r;
      sqi[s][r] = sqv[rr]; ti[s][r] = tgt[rr];
    }

  // wave-uniform diagonal tile per set (or -1)
  int tdiag[2];
#pragma unroll
  for (int s = 0; s < 2; s++) {
    int d = rbase + s * 16 - colbase;
    tdiag[s] = (d >= 0 && d < 512) ? (d >> 4) : -1;
  }

  const unsigned short* bbase = Xb + (size_t)(colbase + l16) * DIM + quad * 8;
  const float* sqp = sqv + colbase + l16;
  const int*   tgp = tgt + colbase + l16;

#define LOADT(BUF, SQ, tn) { \
    const unsigned short* p_ = bbase + (size_t)(tn) * (16 * DIM); \
    BUF[0] = *(const bf16x8*)(p_);      BUF[1] = *(const bf16x8*)(p_ + 32); \
    BUF[2] = *(const bf16x8*)(p_ + 64); BUF[3] = *(const bf16x8*)(p_ + 96); \
    SQ = sqp[(tn) * 16]; }
#define LOADT2(BUF, SQ, TJ, tn) { LOADT(BUF, SQ, tn) TJ = tgp[(tn) * 16]; }

  // ---- sweep 1: per-lane two smallest vals per row (depth-2 pipeline)
  float m1[2][4], m2[2][4];
#pragma unroll
  for (int s = 0; s < 2; s++)
#pragma unroll
    for (int r = 0; r < 4; r++) { m1[s][r] = BIG; m2[s][r] = BIG; }

#define S1COMP(BUF, SQ, tt, live) \
    if (live) { \
      f32x4 a0 = {0.f,0.f,0.f,0.f}, a1 = {0.f,0.f,0.f,0.f}; \
      _Pragma("unroll") \
      for (int kb = 0; kb < 4; kb++) { \
        a0 = __builtin_amdgcn_mfma_f32_16x16x32_bf16(afrag[0][kb], BUF[kb], a0, 0, 0, 0); \
        a1 = __builtin_amdgcn_mfma_f32_16x16x32_bf16(afrag[1][kb], BUF[kb], a1, 0, 0, 0); \
      } \
      _Pragma("unroll") \
      for (int s = 0; s < 2; s++) { \
        _Pragma("unroll") \
        for (int r = 0; r < 4; r++) { \
          float v = fmaf(-2.0f, (s ? a1[r] : a0[r]), SQ); \
          if ((tt) == tdiag[s] && l16 == quad * 4 + r) v = BIG; \
          m2[s][r] = fminf(m2[s][r], fmaxf(m1[s][r], v)); \
          m1[s][r] = fminf(m1[s][r], v); \
        } \
      } \
    }

  {
    bf16x8 b0[4], b1[4], b2[4]; float sq0, sq1, sq2;
    LOADT(b0, sq0, 0)
    LOADT(b1, sq1, 1)
    for (int t = 0; t < NT; t += 3) {
      const int t2 = (t + 2 < NT) ? t + 2 : NT - 1;
      LOADT(b2, sq2, t2)
      S1COMP(b0, sq0, t, true)
      const int t3 = (t + 3 < NT) ? t + 3 : NT - 1;
      LOADT(b0, sq0, t3)
      S1COMP(b1, sq1, t + 1, true)
      const int t4 = (t + 4 < NT) ? t + 4 : NT - 1;
      LOADT(b1, sq1, t4)
      S1COMP(b2, sq2, t2, (t + 2 < NT))
    }
  }
  // publish min2: per row 4 waves x 16 lanes x 2 = 128 candidates (val-space)
#pragma unroll
  for (int s = 0; s < 2; s++)
#pragma unroll
    for (int r = 0; r < 4; r++) {
      int row = s * 16 + quad * 4 + r;
      sh[row * 128 + w * 32 + l16 * 2] = m1[s][r];
      sh[row * 128 + w * 32 + l16 * 2 + 1] = m2[s][r];
    }
  __syncthreads();

  // U[row] = 17th smallest of the 128-candidate subset (radix-select)
  for (int ri = 0; ri < 8; ri++) {
    int row = w * 8 + ri;
    float v17 = kth17_2(sh[row * 128 + lane], sh[row * 128 + 64 + lane]);
    if (lane == 0) Uv[row] = v17;
  }
  __syncthreads();
  float Ur[2][4];
#pragma unroll
  for (int s = 0; s < 2; s++)
#pragma unroll
    for (int r = 0; r < 4; r++) Ur[s][r] = Uv[s * 16 + quad * 4 + r];
  if (lane < ROWS) cnt[w][lane] = 0;   // wave-local; ordered before this wave's appends

  // ---- sweep 2: append val <= U (encode d2 = val + sqi, flag in sign bit)
#define S2COMP(BUF, SQ, TJ, tt, live) \
    if (live) { \
      f32x4 a0 = {0.f,0.f,0.f,0.f}, a1 = {0.f,0.f,0.f,0.f}; \
      _Pragma("unroll") \
      for (int kb = 0; kb < 4; kb++) { \
        a0 = __builtin_amdgcn_mfma_f32_16x16x32_bf16(afrag[0][kb], BUF[kb], a0, 0, 0, 0); \
        a1 = __builtin_amdgcn_mfma_f32_16x16x32_bf16(afrag[1][kb], BUF[kb], a1, 0, 0, 0); \
      } \
      float vv[2][4]; bool any = false; \
      _Pragma("unroll") \
      for (int s = 0; s < 2; s++) { \
        _Pragma("unroll") \
        for (int r = 0; r < 4; r++) { \
          float v = fmaf(-2.0f, (s ? a1[r] : a0[r]), SQ); \
          if ((tt) == tdiag[s] && l16 == quad * 4 + r) v = BIG; \
          vv[s][r] = v; any |= (v <= Ur[s][r]); \
        } \
      } \
      if (__any(any)) { \
        _Pragma("unroll") \
        for (int s = 0; s < 2; s++) { \
          _Pragma("unroll") \
          for (int r = 0; r < 4; r++) { \
            if (vv[s][r] <= Ur[s][r]) { \
              int rl = s * 16 + quad * 4 + r; \
              int pos = atomicAdd(&cnt[w][rl], 1); \
              if (pos < CAPW) { \
                unsigned enc = __float_as_uint(fmaxf(vv[s][r] + sqi[s][r], 0.0f)); \
                if ((TJ) == ti[s][r]) enc |= 0x80000000u; \
                sh[(w * ROWS + rl) * CAPW + pos] = __uint_as_float(enc); \
              } \
            } \
          } \
        } \
      } \
    }

  {
    bf16x8 b0[4], b1[4], b2[4]; float sq0, sq1, sq2; int tj0, tj1, tj2;
    LOADT2(b0, sq0, tj0, 0)
    LOADT2(b1, sq1, tj1, 1)
    for (int t = 0; t < NT; t += 3) {
      const int t2 = (t + 2 < NT) ? t + 2 : NT - 1;
      LOADT2(b2, sq2, tj2, t2)
      S2COMP(b0, sq0, tj0, t, true)
      const int t3 = (t + 3 < NT) ? t + 3 : NT - 1;
      LOADT2(b0, sq0, tj0, t3)
      S2COMP(b1, sq1, tj1, t + 1, true)
      const int t4 = (t + 4 < NT) ? t + 4 : NT - 1;
      LOADT2(b1, sq1, tj1, t4)
      S2COMP(b2, sq2, tj2, t2, (t + 2 < NT))
    }
  }
  __syncthreads();

  // ---- finalize: raw-copy candidate lists (common) or 17-extract (overflow, rare)
  for (int rl = 0; rl < ROWS; rl++) {
    const int c0 = min(cnt[0][rl], CAPW), c1 = min(cnt[1][rl], CAPW),
              c2 = min(cnt[2][rl], CAPW), c3 = min(cnt[3][rl], CAPW);
    const int tot = c0 + c1 + c2 + c3;
    const int grow = rbase + rl;
    float* srow = scr + (size_t)grow * (4 * SEG) + quarter * SEG;
    if (tot <= SEG) {
      const int pre = (w > 0 ? c0 : 0) + (w > 1 ? c1 : 0) + (w > 2 ? c2 : 0);
      const int myc = (w == 0) ? c0 : ((w == 1) ? c1 : ((w == 2) ? c2 : c3));
      if (lane < myc) srow[pre + lane] = sh[(w * ROWS + rl) * CAPW + lane];
      if (tid == 0) cscr[grow * 4 + quarter] = tot;
    } else if (w == (rl & 3)) {
      float e[4]; int m[4];
#pragma unroll
      for (int ww = 0; ww < 4; ww++) {
        int n = min(cnt[ww][rl], CAPW);
        if (lane < n) {
          unsigned u = __float_as_uint(sh[(ww * ROWS + rl) * CAPW + lane]);
          m[ww] = (int)(u >> 31); e[ww] = __uint_as_float(u & 0x7fffffffu);
        } else { e[ww] = BIG; m[ww] = 0; }
      }
      for (int round = 0; round < KSEL; round++) {
        float v = e[0]; int idx = lane;
        if (e[1] < v) { v = e[1]; idx = lane | (1 << 6); }
        if (e[2] < v) { v = e[2]; idx = lane | (2 << 6); }
        if (e[3] < v) { v = e[3]; idx = lane | (3 << 6); }
#pragma unroll
        for (int off = 32; off; off >>= 1) {
          float ov = __shfl_xor(v, off);
          int   oi = __shfl_xor(idx, off);
          if (ov < v || (ov == v && oi < idx)) { v = ov; idx = oi; }
        }
        if ((idx & 63) == lane) {
          int s = idx >> 6;
          unsigned ub = __float_as_uint(e[s]);
          if (m[s]) ub |= 0x80000000u;
          srow[round] = __uint_as_float(ub);
          e[s] = BIG;
        }
      }
      if (lane == 0) cscr[grow * 4 + quarter] = KSEL;
    }
  }
#undef LOADT
#undef LOADT2
#undef S1COMP
#undef S2COMP
}

// ---- per-row merge of 4 quarter-lists (<=128 candidates) + loss epilogue.
// Accumulates into ws acc; the last block (done-counter) writes out directly.
__global__ __launch_bounds__(256) void knn_merge(
    const float* __restrict__ scr, const int* __restrict__ cscr,
    const float* __restrict__ sqv, const int* __restrict__ tgt,
    const int* __restrict__ ccount, const int* __restrict__ j0a,
    const int* __restrict__ j1a, const float* __restrict__ X32,
    unsigned* done, float* acc, float* out) {
  __shared__ float blockAcc[4];
  __shared__ int lastFlag;
  const int tid = threadIdx.x;
  const int w = tid >> 6;
  const int lane = tid & 63;
  if (tid < 4) blockAcc[tid] = 0.0f;
  __syncthreads();
  for (int ri = 0; ri < 4; ri++) {
    const int grow = blockIdx.x * 16 + w * 4 + ri;
    const float* srow = scr + (size_t)grow * (4 * SEG);
    const int ca = cscr[grow * 4 + (lane >> 5)];
    const int cb = cscr[grow * 4 + 2 + (lane >> 5)];
    const int li = lane & 31;
    float e0 = BIG, e1 = BIG; int mm0 = 0, mm1 = 0;
    if (li < ca) {
      unsigned u = __float_as_uint(srow[(lane >> 5) * SEG + li]);
      mm0 = (int)(u >> 31); e0 = __uint_as_float(u & 0x7fffffffu);
    }
    if (li < cb) {
      unsigned u = __float_as_uint(srow[(2 + (lane >> 5)) * SEG + li]);
      mm1 = (int)(u >> 31); e1 = __uint_as_float(u & 0x7fffffffu);
    }
    // exact 17th smallest of the union (radix-select)
    const float t17 = kth17_2(e0, e1);
    bool s0 = (e0 < t17), s1 = (e1 < t17);                // strict, matches reference
    float x0 = s0 ? expf(-sqrtf(fmaxf(e0, 1e-12f))) : 0.0f;
    float x1 = s1 ? expf(-sqrtf(fmaxf(e1, 1e-12f))) : 0.0f;
    float pls = (s0 && mm0 ? x0 : 0.0f) + (s1 && mm1 ? x1 : 0.0f);
    float nls = (s0 && !mm0 ? x0 : 0.0f) + (s1 && !mm1 ? x1 : 0.0f);
    int cpn = ((int)(s0 && mm0) + (int)(s1 && mm1)) * 65536 +
              ((int)(s0 && !mm0) + (int)(s1 && !mm1));
#pragma unroll
    for (int off = 32; off; off >>= 1) {
      pls += __shfl_xor(pls, off); nls += __shfl_xor(nls, off);
      cpn += __shfl_xor(cpn, off);
    }
    const int cp = cpn >> 16, cn = cpn & 0xffff;
    const int c = tgt[grow];
    const int ncl = ccount[c];
    const bool valid = (ncl > 1) && (ncl < NPTS);
    if (valid) {
      float pos_eff;
      if (cp == 0) {
        const int jf = (grow == j0a[c]) ? j1a[c] : j0a[c];
        const float* xi = X32 + (size_t)grow * DIM;
        const float* xj = X32 + (size_t)jf * DIM;
        float pp = xi[lane] * xj[lane] + xi[lane + 64] * xj[lane + 64];
#pragma unroll
        for (int off = 32; off; off >>= 1) pp += __shfl_xor(pp, off);
        const float fb2 = sqv[grow] + sqv[jf] - 2.0f * pp;
        pos_eff = expf(-sqrtf(fmaxf(fb2, 1e-12f)));
      } else {
        pos_eff = pls;
      }
      if (lane == 0) {
        const float loss_i = -logf(pos_eff / (pos_eff + nls));
        const int cpa = (cp == 0) ? 1 : cp;
        atomicAdd(&blockAcc[0], loss_i);
        atomicAdd(&blockAcc[1], (cpa > cn) ? 1.0f : 0.0f);
        atomicAdd(&blockAcc[2], (float)cp);
        atomicAdd(&blockAcc[3], (float)cn);
      }
    }
  }
  __syncthreads();
  if (tid < 4) atomicAdd(&acc[tid], blockAcc[tid]);
  __threadfence();
  __syncthreads();
  if (tid == 0) lastFlag = (atomicAdd(done, 1u) == (unsigned)(gridDim.x - 1));
  __syncthreads();
  if (lastFlag && tid < 4) {
    float v = atomicAdd(&acc[tid], 0.0f);   // device-scope read of the final sum
    out[tid] = v * (1.0f / (float)NPTS);
  }
}

extern "C" void kernel_launch(void* const* d_in, const int* in_sizes, int n_in,
                              void* d_out, int out_size, void* d_ws, size_t ws_size,
                              hipStream_t stream) {
  const float* X = (const float*)d_in[0];
  const long long* targets = (const long long*)d_in[1];
  float* out = (float*)d_out;

  char* ws = (char*)d_ws;
  unsigned short* Xb = (unsigned short*)ws;                        // 2 MiB
  float* sqv    = (float*)   (ws + (2u << 20));                    // 32 KiB
  int*   tgt    = (int*)     (ws + (2u << 20) + (32u << 10));      // 32 KiB
  int*   ccount = (int*)     (ws + (2u << 20) + (64u << 10));      // 512 B
  int*   j0a    = (int*)     (ws + (2u << 20) + (65u << 10));      // 512 B
  int*   j1a    = (int*)     (ws + (2u << 20) + (66u << 10));      // 512 B
  unsigned* done = (unsigned*)(ws + (2u << 20) + (67u << 10));     // 4 B
  float* acc    = (float*)   (ws + (2u << 20) + (67u << 10) + 64); // 16 B
  float* scr = (float*)(ws + (2u << 20) + (128u << 10));           // 8192*4*SEG*4 = 4 MiB
  int* cscr  = (int*)  (ws + (2u << 20) + (128u << 10) + (size_t)NPTS * 4 * SEG * 4); // 128 KiB

  prep<<<2049, 256, 0, stream>>>(X, targets, Xb, sqv, tgt, ccount, j0a, j1a, done, acc);
  knn_main<<<1024, 256, 0, stream>>>(Xb, sqv, tgt, scr, cscr);
  knn_merge<<<512, 256, 0, stream>>>(scr, cscr, sqv, tgt, ccount, j0a, j1a, X, done, acc, out);
}